// Round 9
// baseline (336.611 us; speedup 1.0000x reference)
//
#include <hip/hip_runtime.h>
#include <math.h>

#define N_MARGIN 0.3f
// Gram: 256x256 C-tile, DENSE full grid (16x16 = 256 blocks = 1/CU), 8 waves
// (2M x 4N; per-wave 128x64 = 8x4 frags of mfma_f32_16x16x32_bf16), BK=32.
// T3+T4: 4-slot LDS ring (128KB) staged 3 K-tiles ahead, counted vmcnt(8)
// at tile start (tail 4->0, never 0 in steady state); per tile 4 phases of
// { ds_read frags || 1 gload_lds -> barrier -> lgkmcnt(0) -> setprio(1)
//   8 MFMA setprio(0) -> barrier }.  T5 setprio. T1 XCD swizzle (256%8==0).
// Swizzle (R5/R8-verified, 0 conflicts): LDS rows 64B, phys 16B-chunk =
// logical ^ ((row>>1)&3); linear gload_lds dest + inverse-swizzled global
// source (rule #21); frag read phys = (lane>>4) ^ ((lane>>1)&3).
#define BM 256

typedef __attribute__((ext_vector_type(8))) short bf16x8;
typedef __attribute__((ext_vector_type(4))) float f32x4;
typedef __attribute__((address_space(3))) unsigned int lds_uint;
typedef __attribute__((address_space(1))) unsigned int gbl_uint;

#define WAITV(N) asm volatile("s_waitcnt vmcnt(" #N ")" ::: "memory")
#define LGKM0    asm volatile("s_waitcnt lgkmcnt(0)" ::: "memory")
static __device__ __forceinline__ void wgbar() {
    asm volatile("" ::: "memory");
    __builtin_amdgcn_s_barrier();
    asm volatile("" ::: "memory");
}

// float -> bf16 RNE
static __device__ inline unsigned short f2bf(float f) {
    unsigned int u = __builtin_bit_cast(unsigned int, f);
    u = (u + 0x7fffu + ((u >> 16) & 1u)) >> 16;
    return (unsigned short)u;
}

// ---------------------------------------------------------------------------
// Kernel 1: per-row L2-normalize + bf16 convert, one pass (row in registers).
// ---------------------------------------------------------------------------
__global__ __launch_bounds__(256)
void norm_cvt_k(const float* __restrict__ X, unsigned short* __restrict__ Xb,
                float* __restrict__ rowsq, int d) {
    const int lane = threadIdx.x & 63;
    const int row = blockIdx.x * 4 + (threadIdx.x >> 6);
    const float* xr = X + (size_t)row * d;

    float4 v[8];
    float ss = 0.f;
#pragma unroll
    for (int c = 0; c < 8; ++c) {
        v[c] = *reinterpret_cast<const float4*>(xr + lane * 4 + c * 256);
        ss += v[c].x * v[c].x + v[c].y * v[c].y + v[c].z * v[c].z + v[c].w * v[c].w;
    }
#pragma unroll
    for (int m = 32; m > 0; m >>= 1) ss += __shfl_xor(ss, m);
    float nrm = sqrtf(ss);
    float inv = 1.f / (nrm + 1e-12f);
    if (lane == 0) {
        float s = nrm * inv;
        rowsq[row] = s * s;
    }
    unsigned short* xb = Xb + (size_t)row * d;
#pragma unroll
    for (int c = 0; c < 8; ++c) {
        uint2 o;
        o.x = (unsigned)f2bf(v[c].x * inv) | ((unsigned)f2bf(v[c].y * inv) << 16);
        o.y = (unsigned)f2bf(v[c].z * inv) | ((unsigned)f2bf(v[c].w * inv) << 16);
        *reinterpret_cast<uint2*>(xb + lane * 4 + c * 256) = o;
    }
}

// ---------------------------------------------------------------------------
// Kernel 2: 256^2 dense bf16 MFMA Gram + fused masked-softmax stats.
// ---------------------------------------------------------------------------
__global__ __launch_bounds__(512, 2)
void gram_stats_k(const unsigned short* __restrict__ Xb, const int* __restrict__ tgt,
                  const float* __restrict__ rowsq, float* __restrict__ stats,
                  int n, int d) {
    __shared__ alignas(16) unsigned short As[4][BM * 32];   // 4 ring slots x 16KB
    __shared__ alignas(16) unsigned short Bs[4][BM * 32];

    const int tid = threadIdx.x;
    const int lane = tid & 63;
    const int w = tid >> 6;              // wave 0..7
    const int wr = w >> 2, wc = w & 3;   // 2M x 4N

    // T1: XCD chunking (256 blocks, 256%8==0 -> bijective)
    const int nbx = n / BM;              // 16
    const int nwg = nbx * nbx;           // 256
    const int cpx = nwg >> 3;
    const int swz = ((int)blockIdx.x & 7) * cpx + ((int)blockIdx.x >> 3);
    const int by = swz / nbx, bx = swz % nbx;
    const int row0 = by * BM, col0 = bx * BM;

    f32x4 acc[8][4];
#pragma unroll
    for (int a = 0; a < 8; ++a)
#pragma unroll
        for (int b = 0; b < 4; ++b) acc[a][b] = (f32x4){0.f, 0.f, 0.f, 0.f};

    // staging lane map (R5-verified): instr covers 16 rows x 64B = 1KB;
    // lane l -> row +(l>>2), phys chunk l&3, global chunk (l&3)^((l>>3)&3)
    const int st_r = lane >> 2;
    const int st_g = (lane & 3) ^ ((lane >> 3) & 3);
    // frag read phys chunk (R5-verified, 0 bank conflicts)
    const int rd_p = (lane >> 4) ^ ((lane >> 1) & 3);

    // stage part p (0,1 = A halves; 2,3 = B halves) of K-tile tt
    auto GLOAD = [&](int tt, int p) {
        const int slot = tt & 3;
        const int half = p & 1;
        const int gr = (p >= 2 ? col0 : row0) + half * 128 + w * 16 + st_r;
        const unsigned short* g = Xb + (size_t)gr * d + tt * 32 + st_g * 8;
        unsigned short* lp = (p >= 2 ? &Bs[slot][0] : &As[slot][0]) +
                             (half * 512 + w * 64) * 8;
        __builtin_amdgcn_global_load_lds((const gbl_uint*)g, (lds_uint*)lp, 16, 0, 0);
    };

    const int nt = d / 32;               // 64 K-tiles

    // one K-tile: WAITV(wn) -> bar -> 4 interleaved phases
    auto TILE = [&](int t, int wn, bool st) {
        if (wn == 8) { WAITV(8); } else if (wn == 4) { WAITV(4); } else { WAITV(0); }
        wgbar();                          // all waves' tile-t staging visible
        const int slot = t & 3;
        bf16x8 bfr[4];
#pragma unroll
        for (int p = 0; p < 4; ++p) {
            const int fr0 = 2 * p;
            if (p == 0) {
#pragma unroll
                for (int nc = 0; nc < 4; ++nc) {
                    int rB = wc * 64 + nc * 16 + (lane & 15);
                    bfr[nc] = *reinterpret_cast<const bf16x8*>(
                        &Bs[slot][rB * 32 + rd_p * 8]);
                }
            }
            int rA0 = wr * 128 + fr0 * 16 + (lane & 15);
            bf16x8 a0 = *reinterpret_cast<const bf16x8*>(
                &As[slot][rA0 * 32 + rd_p * 8]);
            bf16x8 a1 = *reinterpret_cast<const bf16x8*>(
                &As[slot][(rA0 + 16) * 32 + rd_p * 8]);
            if (st) GLOAD(t + 3, p);      // one staging instr per phase
            wgbar();
            LGKM0;
            __builtin_amdgcn_s_setprio(1);
#pragma unroll
            for (int nc = 0; nc < 4; ++nc)
                acc[fr0][nc] = __builtin_amdgcn_mfma_f32_16x16x32_bf16(
                    a0, bfr[nc], acc[fr0][nc], 0, 0, 0);
#pragma unroll
            for (int nc = 0; nc < 4; ++nc)
                acc[fr0 + 1][nc] = __builtin_amdgcn_mfma_f32_16x16x32_bf16(
                    a1, bfr[nc], acc[fr0 + 1][nc], 0, 0, 0);
            __builtin_amdgcn_s_setprio(0);
            wgbar();
        }
    };

    // prologue: stage tiles 0,1,2 (12 loads/wave in flight)
#pragma unroll
    for (int pt = 0; pt < 3; ++pt)
#pragma unroll
        for (int p = 0; p < 4; ++p) GLOAD(pt, p);

    for (int t = 0; t < nt - 2; ++t) TILE(t, 8, t < nt - 3);
    TILE(nt - 2, 4, false);
    TILE(nt - 1, 0, false);

    // ------------------------------------------------------------------
    // Epilogue (dense grid -> row stats only; mirror handled by block
    // (bx,by)). C row = row0 + wr*128 + fr*16 + (lane>>4)*4 + j;
    // col = col0 + wc*64 + nc*16 + (lane&15).
    // ------------------------------------------------------------------
    int tjv[4]; float qjv[4];
#pragma unroll
    for (int nc = 0; nc < 4; ++nc) {
        int gcol = col0 + wc * 64 + nc * 16 + (lane & 15);
        tjv[nc] = tgt[gcol];
        qjv[nc] = rowsq[gcol];
    }
#pragma unroll
    for (int fr = 0; fr < 8; ++fr) {
#pragma unroll
        for (int j = 0; j < 4; ++j) {
            int grow = row0 + wr * 128 + fr * 16 + (lane >> 4) * 4 + j;
            int ti = tgt[grow];
            float sqi = rowsq[grow];
            float pd = 0.f, pn = 0.f, nd = 0.f, nn = 0.f;
#pragma unroll
            for (int nc = 0; nc < 4; ++nc) {
                int gcol = col0 + wc * 64 + nc * 16 + (lane & 15);
                float g = acc[fr][nc][j];
                float d2 = sqi + qjv[nc] - 2.f * g;
                float dist = sqrtf(fmaxf(d2, 1e-12f));
                if (ti == tjv[nc]) {
                    if (grow != gcol) {
                        float e = __expf(dist);
                        pd += e; pn += e * dist;
                    }
                } else {
                    float e = __expf(-dist);
                    nd += e; nn += e * dist;
                }
            }
            for (int m = 1; m < 16; m <<= 1) {
                pd += __shfl_xor(pd, m);
                pn += __shfl_xor(pn, m);
                nd += __shfl_xor(nd, m);
                nn += __shfl_xor(nn, m);
            }
            if ((lane & 15) == 0) {
                atomicAdd(&stats[grow * 4 + 0], pd);
                atomicAdd(&stats[grow * 4 + 1], pn);
                atomicAdd(&stats[grow * 4 + 2], nd);
                atomicAdd(&stats[grow * 4 + 3], nn);
            }
        }
    }
}

// ---------------------------------------------------------------------------
// Kernel 3: finalize — loss = mean(relu(pos + MARGIN - neg))
// ---------------------------------------------------------------------------
__global__ void finalize_k(const float* __restrict__ stats, float* __restrict__ out, int n) {
    float s = 0.f;
    for (int i = threadIdx.x; i < n; i += blockDim.x) {
        float4 st = *reinterpret_cast<const float4*>(&stats[i * 4]);
        float v = st.y / st.x + N_MARGIN - st.w / st.z;
        s += fmaxf(v, 0.f);
    }
    for (int m = 32; m > 0; m >>= 1) s += __shfl_down(s, m);
    __shared__ float sp[4];
    int lane = threadIdx.x & 63, wv = threadIdx.x >> 6;
    if (lane == 0) sp[wv] = s;
    __syncthreads();
    if (threadIdx.x == 0) out[0] = (sp[0] + sp[1] + sp[2] + sp[3]) / (float)n;
}

extern "C" void kernel_launch(void* const* d_in, const int* in_sizes, int n_in,
                              void* d_out, int out_size, void* d_ws, size_t ws_size,
                              hipStream_t stream) {
    const float* X = (const float*)d_in[0];
    const int* tgt = (const int*)d_in[1];
    const int n = in_sizes[1];             // 4096
    const int d = in_sizes[0] / n;         // 2048

    unsigned short* Xb = (unsigned short*)d_ws;          // n*d bf16 (16 MB)
    float* rowsq = (float*)(Xb + (size_t)n * d);         // n floats
    float* stats = rowsq + n;                            // 4n floats

    hipMemsetAsync(stats, 0, (size_t)n * 4 * sizeof(float), stream);
    norm_cvt_k<<<n / 4, 256, 0, stream>>>(X, Xb, rowsq, d);
    const int nbx = n / BM;                              // 16
    gram_stats_k<<<nbx * nbx, 512, 0, stream>>>(Xb, tgt, rowsq, stats, n, d);
    finalize_k<<<1, 256, 0, stream>>>(stats, (float*)d_out, n);
}